// Round 5
// baseline (389.091 us; speedup 1.0000x reference)
//
#include <hip/hip_runtime.h>

#define NN 100000
#define EE 1600000
#define DD 128
#define NB 512        // buckets = nodes >> 8
#define CAP 4608      // bucket capacity (mean 3125 dst-bucket ~4092, +8 sigma)
#define CHUNK 8192    // edges per split block

typedef __attribute__((ext_vector_type(8))) short short8v;          // MFMA A/B frag (8 bf16)
typedef __attribute__((ext_vector_type(4))) float f32x4;            // MFMA C/D frag
typedef __attribute__((ext_vector_type(8))) unsigned short ushort8v;

static __device__ __forceinline__ unsigned short f2bf(float x) {    // round-to-nearest-even
  unsigned u = __builtin_bit_cast(unsigned, x);
  return (unsigned short)((u + 0x7FFFu + ((u >> 16) & 1u)) >> 16);
}
static __device__ __forceinline__ float bf2f(unsigned short u) {
  return __builtin_bit_cast(float, (unsigned)u << 16);
}

// ---- init bucket cursors ----
__global__ __launch_bounds__(512) void initcur_k(int* __restrict__ cur_d,
                                                 int* __restrict__ cur_s) {
  int t = threadIdx.x;
  cur_d[t] = t * CAP;
  cur_s[t] = t * CAP;
}

// ---- pass 1: split edges into 512 buckets by high 9 bits (LDS hist + rank) ----
__global__ __launch_bounds__(256) void split_k(const int* __restrict__ src,
                                               const int* __restrict__ dst,
                                               int* __restrict__ cur_d,
                                               int* __restrict__ cur_s,
                                               unsigned* __restrict__ tmp_d,
                                               unsigned char* __restrict__ tmp_s) {
  __shared__ int hd[NB], hs[NB], bd[NB], bs[NB];
  int t = threadIdx.x;
  int base = blockIdx.x * CHUNK;
  int end = base + CHUNK < EE ? base + CHUNK : EE;
  for (int b = t; b < NB; b += 256) { hd[b] = 0; hs[b] = 0; }
  __syncthreads();
  for (int i = base + t; i < end; i += 256) {
    atomicAdd(&hd[dst[i] >> 8], 1);
    atomicAdd(&hs[src[i] >> 8], 1);
  }
  __syncthreads();
  for (int b = t; b < NB; b += 256) {
    bd[b] = hd[b] ? atomicAdd(&cur_d[b], hd[b]) : 0;
    bs[b] = hs[b] ? atomicAdd(&cur_s[b], hs[b]) : 0;
    hd[b] = 0;  // reuse as rank counters
    hs[b] = 0;
  }
  __syncthreads();
  for (int i = base + t; i < end; i += 256) {
    int s = src[i];
    int d = dst[i];
    int bin = d >> 8;
    int r = atomicAdd(&hd[bin], 1);
    int pos = bd[bin] + r;
    if (pos < (bin + 1) * CAP) tmp_d[pos] = ((unsigned)(d & 255) << 17) | (unsigned)s;
    bin = s >> 8;
    r = atomicAdd(&hs[bin], 1);
    pos = bs[bin] + r;
    if (pos < (bin + 1) * CAP) tmp_s[pos] = (unsigned char)(s & 255);
  }
}

// ---- exclusive scan of 512 bucket counts -> dense CSR starts ----
__global__ __launch_bounds__(512) void scan512_k(const int* __restrict__ cur_d,
                                                 int* __restrict__ dstart) {
  __shared__ int lds[512];
  int t = threadIdx.x;
  int v = cur_d[t] - t * CAP;
  v = v < CAP ? v : CAP;
  lds[t] = v;
  __syncthreads();
  int run = v;
  for (int off = 1; off < 512; off <<= 1) {
    int y = (t >= off) ? lds[t - off] : 0;
    __syncthreads();
    run += y;
    lds[t] = run;
    __syncthreads();
  }
  dstart[t] = run - v;
}

// ---- pass 2 (dst): per-bucket LDS counting sort -> dense csr + rows + norm_in ----
__global__ __launch_bounds__(256) void bucket_dst_k(const unsigned* __restrict__ tmp_d,
                                                    const int* __restrict__ cur_d,
                                                    const int* __restrict__ dstart,
                                                    int* __restrict__ csr,
                                                    int* __restrict__ row_s,
                                                    int* __restrict__ row_e,
                                                    float* __restrict__ norm_in) {
  __shared__ unsigned stage[CAP];
  __shared__ int h[256], sc[256], rk[256];
  int b = blockIdx.x;
  int t = threadIdx.x;
  int cnt = cur_d[b] - b * CAP;
  cnt = cnt < CAP ? cnt : CAP;
  int ds = dstart[b];
  for (int i = t; i < cnt; i += 256) stage[i] = tmp_d[b * CAP + i];
  h[t] = 0;
  __syncthreads();
  for (int i = t; i < cnt; i += 256) atomicAdd(&h[stage[i] >> 17], 1);
  __syncthreads();
  int v = h[t];
  sc[t] = v;
  __syncthreads();
  int run = v;
  for (int off = 1; off < 256; off <<= 1) {
    int y = (t >= off) ? sc[t - off] : 0;
    __syncthreads();
    run += y;
    sc[t] = run;
    __syncthreads();
  }
  int excl = run - v;
  int n = b * 256 + t;
  if (n < NN) {
    row_s[n] = ds + excl;
    row_e[n] = ds + excl + v;
    norm_in[n] = rsqrtf((float)(v > 1 ? v : 1));
  }
  rk[t] = excl;
  __syncthreads();
  for (int i = t; i < cnt; i += 256) {
    unsigned w = stage[i];
    int r = atomicAdd(&rk[w >> 17], 1);
    csr[ds + r] = (int)(w & 0x1FFFFu);
  }
}

// ---- pass 2 (src): per-bucket byte histogram -> norm_out ----
__global__ __launch_bounds__(256) void bucket_src_k(const unsigned char* __restrict__ tmp_s,
                                                    const int* __restrict__ cur_s,
                                                    float* __restrict__ norm_out) {
  __shared__ int h[256];
  int b = blockIdx.x;
  int t = threadIdx.x;
  int cnt = cur_s[b] - b * CAP;
  cnt = cnt < CAP ? cnt : CAP;
  h[t] = 0;
  __syncthreads();
  const unsigned char* p = tmp_s + b * CAP;
  for (int i = t; i < cnt; i += 256) atomicAdd(&h[p[i]], 1);
  __syncthreads();
  int n = b * 256 + t;
  if (n < NN) norm_out[n] = rsqrtf((float)(h[t] > 1 ? h[t] : 1));
}

// ---- W fp32 -> bf16 (16384 elems, 16 blocks) ----
__global__ __launch_bounds__(256) void wconv_k(const float* __restrict__ w,
                                               unsigned short* __restrict__ o) {
  int i = blockIdx.x * 256 + threadIdx.x;
  float4 v = *reinterpret_cast<const float4*>(w + i * 4);
  ushort4 pk = make_ushort4(f2bf(v.x), f2bf(v.y), f2bf(v.z), f2bf(v.w));
  *reinterpret_cast<ushort4*>(o + i * 4) = pk;
}

// ---- h1 = bf16(feat * norm_out) ----
__global__ __launch_bounds__(256) void hconv_k(const float* __restrict__ feat,
                                               const float* __restrict__ no,
                                               unsigned short* __restrict__ h) {
  int i = blockIdx.x * 256 + threadIdx.x;
  int node = i >> 4;
  int lane = i & 15;
  float n = no[node];
  const float* p = feat + node * DD + lane * 8;
  float4 a = *reinterpret_cast<const float4*>(p);
  float4 b = *reinterpret_cast<const float4*>(p + 4);
  ushort8v o;
  o[0] = f2bf(a.x * n); o[1] = f2bf(a.y * n); o[2] = f2bf(a.z * n); o[3] = f2bf(a.w * n);
  o[4] = f2bf(b.x * n); o[5] = f2bf(b.y * n); o[6] = f2bf(b.z * n); o[7] = f2bf(b.w * n);
  *reinterpret_cast<ushort8v*>(h + node * DD + lane * 8) = o;
}

// ---- fused layer: gather-sum straight into MFMA B-frags, swapped-operand MFMA,
//      per-lane float4 epilogue. No LDS, no barriers.
// Wave handles 16 nodes x 128 cols. Lane (l15,kgrp): node=l15, k-chunks {kgrp+4t}.
// D^T = mfma(A=W-frag, B=agg-frag): D col = node (l15), D row = out col j = kgrp*4+r.
__global__ __launch_bounds__(256) void layer_k(const unsigned short* __restrict__ h,
                                               const int* __restrict__ csr,
                                               const int* __restrict__ row_s,
                                               const int* __restrict__ row_e,
                                               const unsigned short* __restrict__ Wb,
                                               const float* __restrict__ bias,
                                               const float* __restrict__ nin,
                                               const float* __restrict__ nout,
                                               const float* __restrict__ resid,
                                               float* __restrict__ outp,
                                               unsigned short* __restrict__ hnext,
                                               int mode) {
  int wid = threadIdx.x >> 6;
  int lane = threadIdx.x & 63;
  int l15 = lane & 15;
  int kgrp = lane >> 4;
  int node = blockIdx.x * 64 + wid * 16 + l15;
  int nodec = node < NN ? node : NN - 1;

  // ---- gather phase: accumulate this lane's 4 k-chunks (16B each) over the row
  int e0 = row_s[nodec];
  int e1 = row_e[nodec];
  float a0[8] = {0,0,0,0,0,0,0,0}, a1[8] = {0,0,0,0,0,0,0,0};
  float a2[8] = {0,0,0,0,0,0,0,0}, a3[8] = {0,0,0,0,0,0,0,0};
  const unsigned short* hb = h + kgrp * 8;  // chunk (kgrp+4t) -> short off kgrp*8 + 32t
  int e = e0;
  for (; e + 2 <= e1; e += 2) {
    int s0 = csr[e];
    int s1 = csr[e + 1];
    const unsigned short* p0 = hb + (size_t)s0 * DD;
    const unsigned short* p1 = hb + (size_t)s1 * DD;
    ushort8v u0 = *reinterpret_cast<const ushort8v*>(p0);
    ushort8v u1 = *reinterpret_cast<const ushort8v*>(p0 + 32);
    ushort8v u2 = *reinterpret_cast<const ushort8v*>(p0 + 64);
    ushort8v u3 = *reinterpret_cast<const ushort8v*>(p0 + 96);
    ushort8v v0 = *reinterpret_cast<const ushort8v*>(p1);
    ushort8v v1 = *reinterpret_cast<const ushort8v*>(p1 + 32);
    ushort8v v2 = *reinterpret_cast<const ushort8v*>(p1 + 64);
    ushort8v v3 = *reinterpret_cast<const ushort8v*>(p1 + 96);
#pragma unroll
    for (int i = 0; i < 8; ++i) {
      a0[i] += bf2f(u0[i]) + bf2f(v0[i]);
      a1[i] += bf2f(u1[i]) + bf2f(v1[i]);
      a2[i] += bf2f(u2[i]) + bf2f(v2[i]);
      a3[i] += bf2f(u3[i]) + bf2f(v3[i]);
    }
  }
  if (e < e1) {
    int s0 = csr[e];
    const unsigned short* p0 = hb + (size_t)s0 * DD;
    ushort8v u0 = *reinterpret_cast<const ushort8v*>(p0);
    ushort8v u1 = *reinterpret_cast<const ushort8v*>(p0 + 32);
    ushort8v u2 = *reinterpret_cast<const ushort8v*>(p0 + 64);
    ushort8v u3 = *reinterpret_cast<const ushort8v*>(p0 + 96);
#pragma unroll
    for (int i = 0; i < 8; ++i) {
      a0[i] += bf2f(u0[i]);
      a1[i] += bf2f(u1[i]);
      a2[i] += bf2f(u2[i]);
      a3[i] += bf2f(u3[i]);
    }
  }
  // pack to bf16 B-fragments (same rounding point as the old agg buffer)
  short8v b0, b1, b2, b3;
#pragma unroll
  for (int i = 0; i < 8; ++i) {
    b0[i] = (short)f2bf(a0[i]);
    b1[i] = (short)f2bf(a1[i]);
    b2[i] = (short)f2bf(a2[i]);
    b3[i] = (short)f2bf(a3[i]);
  }

  float ninv = nin[nodec];
  float noutv = mode ? nout[nodec] : 0.f;

  // ---- MFMA + epilogue: 8 col-tiles of 16
  for (int ct = 0; ct < 8; ++ct) {
    const unsigned short* wp = Wb + (size_t)(ct * 16 + l15) * DD + kgrp * 8;
    short8v w0 = *reinterpret_cast<const short8v*>(wp);
    short8v w1 = *reinterpret_cast<const short8v*>(wp + 32);
    short8v w2 = *reinterpret_cast<const short8v*>(wp + 64);
    short8v w3 = *reinterpret_cast<const short8v*>(wp + 96);
    f32x4 c = {0.f, 0.f, 0.f, 0.f};
    c = __builtin_amdgcn_mfma_f32_16x16x32_bf16(w0, b0, c, 0, 0, 0);
    c = __builtin_amdgcn_mfma_f32_16x16x32_bf16(w1, b1, c, 0, 0, 0);
    c = __builtin_amdgcn_mfma_f32_16x16x32_bf16(w2, b2, c, 0, 0, 0);
    c = __builtin_amdgcn_mfma_f32_16x16x32_bf16(w3, b3, c, 0, 0, 0);

    if (node < NN) {
      int j = ct * 16 + kgrp * 4;
      float4 bj = *reinterpret_cast<const float4*>(bias + j);
      size_t idx = (size_t)node * DD + j;
      float4 v;
      v.x = (c[0] + bj.x) * ninv;
      v.y = (c[1] + bj.y) * ninv;
      v.z = (c[2] + bj.z) * ninv;
      v.w = (c[3] + bj.w) * ninv;
      if (mode) {
        float4 rs = *reinterpret_cast<const float4*>(resid + idx);
        v.x = fmaxf(v.x + rs.x, 0.f);
        v.y = fmaxf(v.y + rs.y, 0.f);
        v.z = fmaxf(v.z + rs.z, 0.f);
        v.w = fmaxf(v.w + rs.w, 0.f);
        *reinterpret_cast<float4*>(outp + idx) = v;
        ushort4 hn = make_ushort4(f2bf(v.x * noutv), f2bf(v.y * noutv),
                                  f2bf(v.z * noutv), f2bf(v.w * noutv));
        *reinterpret_cast<ushort4*>(hnext + idx) = hn;
      } else {
        *reinterpret_cast<float4*>(outp + idx) = v;
      }
    }
  }
}

extern "C" void kernel_launch(void* const* d_in, const int* in_sizes, int n_in,
                              void* d_out, int out_size, void* d_ws, size_t ws_size,
                              hipStream_t stream) {
  const float* feat = (const float*)d_in[0];
  const int* src = (const int*)d_in[1];
  const int* dst = (const int*)d_in[2];
  const float* W1 = (const float*)d_in[3];
  const float* b1 = (const float*)d_in[4];
  const float* W2 = (const float*)d_in[5];
  const float* b2 = (const float*)d_in[6];
  const float* W3 = (const float*)d_in[7];
  const float* b3 = (const float*)d_in[8];
  float* out = (float*)d_out;

  // ws layout
  int* row_s = (int*)d_ws;                   // N
  int* row_e = row_s + NN;                   // N
  float* norm_out = (float*)(row_e + NN);    // N
  float* norm_in = norm_out + NN;            // N
  int* cur_d = (int*)(norm_in + NN);         // 512
  int* cur_s = cur_d + NB;                   // 512
  int* dstart = cur_s + NB;                  // 512
  int* pad = dstart + NB;                    // 512
  unsigned short* Wbf = (unsigned short*)pad;          // 3*16384 bf16
  int* csr = (int*)(Wbf + 3 * 16384);                  // E ints
  unsigned short* hbuf = (unsigned short*)(csr + EE);  // N*D bf16 (25.6MB)
  unsigned short* hbuf2 = hbuf + (size_t)NN * DD;      // N*D bf16 (ping-pong)

  // bucket temporaries live in d_out (dead before layer-1 writes it)
  unsigned* tmp_d = (unsigned*)d_out;                                   // 9.4MB
  unsigned char* tmp_s = (unsigned char*)d_out + (size_t)NB * CAP * 4;  // 2.4MB

  initcur_k<<<1, 512, 0, stream>>>(cur_d, cur_s);
  split_k<<<(EE + CHUNK - 1) / CHUNK, 256, 0, stream>>>(src, dst, cur_d, cur_s, tmp_d, tmp_s);
  scan512_k<<<1, 512, 0, stream>>>(cur_d, dstart);
  bucket_dst_k<<<NB, 256, 0, stream>>>(tmp_d, cur_d, dstart, csr, row_s, row_e, norm_in);
  bucket_src_k<<<NB, 256, 0, stream>>>(tmp_s, cur_s, norm_out);

  wconv_k<<<16, 256, 0, stream>>>(W1, Wbf);
  wconv_k<<<16, 256, 0, stream>>>(W2, Wbf + 16384);
  wconv_k<<<16, 256, 0, stream>>>(W3, Wbf + 32768);
  hconv_k<<<6250, 256, 0, stream>>>(feat, norm_out, hbuf);

  const int GB = (NN + 63) / 64;  // 1563
  // layer 1: h=hbuf -> out, resid=feat, emit hbuf2
  layer_k<<<GB, 256, 0, stream>>>(hbuf, csr, row_s, row_e, Wbf, b1, norm_in,
                                  norm_out, feat, out, hbuf2, 1);
  // layer 2: h=hbuf2 -> out (in-place resid=out), emit hbuf
  layer_k<<<GB, 256, 0, stream>>>(hbuf2, csr, row_s, row_e, Wbf + 16384, b2, norm_in,
                                  norm_out, out, out, hbuf, 1);
  // layer 3: h=hbuf -> out, no resid/act/hnext
  layer_k<<<GB, 256, 0, stream>>>(hbuf, csr, row_s, row_e, Wbf + 32768, b3, norm_in,
                                  norm_out, nullptr, out, nullptr, 0);
}